// Round 1
// baseline (396.141 us; speedup 1.0000x reference)
//
#include <hip/hip_runtime.h>
#include <hip/hip_bf16.h>

#define N_EDGES_C 600000
#define D_C 128

typedef __attribute__((ext_vector_type(8))) short short8;
typedef __attribute__((ext_vector_type(4))) float f32x4;

__device__ inline unsigned short f2bf(float f) {
    unsigned int u = __builtin_bit_cast(unsigned int, f);
    u += 0x7FFF + ((u >> 16) & 1);          // round-nearest-even
    return (unsigned short)(u >> 16);
}

// W1 (f32, row-major [k][n], 256x256) -> W1T bf16 [n][k]
__global__ void prep_w1t(const float* __restrict__ W1, unsigned short* __restrict__ w1t) {
    int n = blockIdx.x;    // 0..255
    int k = threadIdx.x;   // 0..255
    w1t[n * 256 + k] = f2bf(W1[k * 256 + n]);
}

__global__ __launch_bounds__(256, 2) void edge_mlp(
    const float* __restrict__ emd,
    const int* __restrict__ eidx,
    const unsigned short* __restrict__ w1t,
    const float* __restrict__ b1,
    const float* __restrict__ W2,
    const float* __restrict__ b2,
    float* __restrict__ out)
{
    extern __shared__ unsigned char smem[];   // A tile: 128 rows x 512B bf16, xor-swizzled
    const int e0 = blockIdx.x * 128;
    const int t = threadIdx.x;

    // ---- stage A tile: rows = edges, cols 0..127 src embed, 128..255 dst embed ----
    #pragma unroll 4
    for (int p = 0; p < 32; ++p) {
        int c = p * 256 + t;          // 8-byte chunk id; 64 chunks per row
        int row = c >> 6;
        int cb  = c & 63;
        int e = e0 + row; if (e >= N_EDGES_C) e = N_EDGES_C - 1;
        int which = cb >> 5;          // 0=src, 1=dst
        int idx = eidx[e * 2 + which];
        const float4 v = *reinterpret_cast<const float4*>(emd + (size_t)idx * D_C + (cb & 31) * 4);
        ushort4 pk;
        pk.x = f2bf(v.x); pk.y = f2bf(v.y); pk.z = f2bf(v.z); pk.w = f2bf(v.w);
        int boff = (row * 512 + cb * 8) ^ ((row & 7) << 4);
        *reinterpret_cast<ushort4*>(smem + boff) = pk;
    }
    __syncthreads();

    const int lane = t & 63;
    const int wv   = t >> 6;      // 4 waves, each owns 32 edge rows
    const int l15  = lane & 15;
    const int lg   = lane >> 4;   // 0..3

    float pr[2][4] = {{0.f,0.f,0.f,0.f},{0.f,0.f,0.f,0.f}};

    const int r0 = wv * 32 + l15;
    const int r1 = r0 + 16;
    const int abase0 = r0 * 512 + lg * 16;
    const int abase1 = r1 * 512 + lg * 16;
    const int axor0 = (r0 & 7) << 4;
    const int axor1 = (r1 & 7) << 4;

    #pragma unroll
    for (int nfc = 0; nfc < 4; ++nfc) {
        f32x4 acc[2][4];
        #pragma unroll
        for (int rf = 0; rf < 2; ++rf)
            #pragma unroll
            for (int j = 0; j < 4; ++j) acc[rf][j] = (f32x4){0.f,0.f,0.f,0.f};

        #pragma unroll
        for (int kk = 0; kk < 8; ++kk) {
            short8 a0 = *reinterpret_cast<const short8*>(smem + ((abase0 + kk * 64) ^ axor0));
            short8 a1 = *reinterpret_cast<const short8*>(smem + ((abase1 + kk * 64) ^ axor1));
            #pragma unroll
            for (int n4 = 0; n4 < 4; ++n4) {
                int n = (nfc * 4 + n4) * 16 + l15;
                short8 bfr = *reinterpret_cast<const short8*>(w1t + n * 256 + kk * 32 + lg * 8);
                acc[0][n4] = __builtin_amdgcn_mfma_f32_16x16x32_bf16(a0, bfr, acc[0][n4], 0, 0, 0);
                acc[1][n4] = __builtin_amdgcn_mfma_f32_16x16x32_bf16(a1, bfr, acc[1][n4], 0, 0, 0);
            }
        }
        // fuse: relu(acc + b1) * W2 -> per-lane partial logits
        #pragma unroll
        for (int n4 = 0; n4 < 4; ++n4) {
            int n = (nfc * 4 + n4) * 16 + l15;
            float b1v = b1[n];
            float w2v = W2[n];
            #pragma unroll
            for (int rf = 0; rf < 2; ++rf)
                #pragma unroll
                for (int g = 0; g < 4; ++g) {
                    float h = acc[rf][n4][g] + b1v;
                    h = h > 0.f ? h : 0.f;
                    pr[rf][g] += h * w2v;
                }
        }
    }

    // reduce across the 16 lanes of the l15 dimension (columns)
    #pragma unroll
    for (int m = 8; m >= 1; m >>= 1) {
        #pragma unroll
        for (int rf = 0; rf < 2; ++rf)
            #pragma unroll
            for (int g = 0; g < 4; ++g)
                pr[rf][g] += __shfl_xor(pr[rf][g], m, 64);
    }

    if (l15 == 0) {
        float bb = b2[0];
        #pragma unroll
        for (int rf = 0; rf < 2; ++rf)
            #pragma unroll
            for (int g = 0; g < 4; ++g) {
                int e = e0 + wv * 32 + rf * 16 + lg * 4 + g;
                if (e < N_EDGES_C) {
                    float logit = pr[rf][g] + bb;
                    out[e] = 1.0f / (1.0f + __expf(-logit));
                }
            }
    }
}

extern "C" void kernel_launch(void* const* d_in, const int* in_sizes, int n_in,
                              void* d_out, int out_size, void* d_ws, size_t ws_size,
                              hipStream_t stream) {
    const float* emd  = (const float*)d_in[0];
    const int*   eidx = (const int*)d_in[1];
    const float* W1   = (const float*)d_in[2];
    const float* b1   = (const float*)d_in[3];
    const float* W2   = (const float*)d_in[4];
    const float* b2   = (const float*)d_in[5];
    float* out = (float*)d_out;
    unsigned short* w1t = (unsigned short*)d_ws;   // 256*256 bf16 = 128KB

    prep_w1t<<<256, 256, 0, stream>>>(W1, w1t);

    const int nblocks = (N_EDGES_C + 127) / 128;   // 4688
    edge_mlp<<<nblocks, 256, 65536, stream>>>(emd, eidx, w1t, b1, W2, b2, out);
}

// Round 2
// 135.055 us; speedup vs baseline: 2.9332x; 2.9332x over previous
//
#include <hip/hip_runtime.h>
#include <hip/hip_bf16.h>

#define N_EDGES_C 600000
#define D_C 128

typedef __attribute__((ext_vector_type(8))) short short8;
typedef __attribute__((ext_vector_type(4))) float f32x4;

__device__ inline unsigned short f2bf(float f) {
    unsigned int u = __builtin_bit_cast(unsigned int, f);
    u += 0x7FFF + ((u >> 16) & 1);          // round-nearest-even
    return (unsigned short)(u >> 16);
}

// Fragment-ordered W1 (bf16): w1f[((nf*8+kk)*64 + lane)*8 + j] =
//   W1[(kk*32 + (lane>>4)*8 + j) * 256 + nf*16 + (lane&15)]
// so each (nf,kk) B-fragment is one contiguous, coalesced 1KB wave load.
__global__ void prep_w1f(const float* __restrict__ W1, unsigned short* __restrict__ w1f) {
    int o = blockIdx.x * 256 + threadIdx.x;   // 0..65535
    int j    = o & 7;
    int lane = (o >> 3) & 63;
    int kk   = (o >> 9) & 7;
    int nf   = o >> 12;
    int k = kk * 32 + (lane >> 4) * 8 + j;
    int n = nf * 16 + (lane & 15);
    w1f[o] = f2bf(W1[k * 256 + n]);
}

__global__ __launch_bounds__(256, 4) void edge_mlp(
    const float* __restrict__ emd,
    const int* __restrict__ eidx,
    const unsigned short* __restrict__ w1f,
    const float* __restrict__ b1,
    const float* __restrict__ W2,
    const float* __restrict__ b2,
    float* __restrict__ out)
{
    extern __shared__ unsigned char smem[];            // A tile: 64 rows x 512B bf16, xor-swizzled
    float* partial = (float*)(smem + 64 * 512);        // [4 waves][64 rows] f32 = 1KB

    const int e0 = blockIdx.x * 64;
    const int t = threadIdx.x;

    // ---- stage A tile: row=edge, cols 0..127 src embed, 128..255 dst embed ----
    // per p: wave wv stages one full row (row = p*4+wv); eidx load is wave-uniform
    #pragma unroll
    for (int p = 0; p < 16; ++p) {
        int c   = p * 256 + t;        // 16B-f32-chunk id; 64 chunks per row
        int row = c >> 6;
        int cb  = c & 63;
        int idx = eidx[(e0 + row) * 2 + (cb >> 5)];
        const float4 v = *reinterpret_cast<const float4*>(emd + (size_t)idx * D_C + (cb & 31) * 4);
        ushort4 pk;
        pk.x = f2bf(v.x); pk.y = f2bf(v.y); pk.z = f2bf(v.z); pk.w = f2bf(v.w);
        int boff = (row * 512 + cb * 8) ^ ((row & 7) << 4);
        *reinterpret_cast<ushort4*>(smem + boff) = pk;
    }
    __syncthreads();

    const int lane = t & 63;
    const int wv   = t >> 6;      // 4 waves, each owns 64 output cols (4 n-frags)
    const int l15  = lane & 15;
    const int lg   = lane >> 4;   // 0..3

    f32x4 acc[4][4];              // [m-frag][n-frag]
    #pragma unroll
    for (int m = 0; m < 4; ++m)
        #pragma unroll
        for (int n4 = 0; n4 < 4; ++n4) acc[m][n4] = (f32x4){0.f, 0.f, 0.f, 0.f};

    #pragma unroll
    for (int kk = 0; kk < 8; ++kk) {
        short8 a[4];
        #pragma unroll
        for (int m = 0; m < 4; ++m) {
            int r = m * 16 + l15;
            a[m] = *reinterpret_cast<const short8*>(
                smem + ((r * 512 + kk * 64 + lg * 16) ^ ((r & 7) << 4)));
        }
        #pragma unroll
        for (int n4 = 0; n4 < 4; ++n4) {
            int nf = wv * 4 + n4;
            short8 b = *reinterpret_cast<const short8*>(w1f + ((nf * 8 + kk) * 64 + lane) * 8);
            #pragma unroll
            for (int m = 0; m < 4; ++m)
                acc[m][n4] = __builtin_amdgcn_mfma_f32_16x16x32_bf16(a[m], b, acc[m][n4], 0, 0, 0);
        }
    }

    // ---- fused epilogue: relu(acc + b1) * W2 -> per-lane partial logits ----
    float pr[4][4];
    #pragma unroll
    for (int m = 0; m < 4; ++m)
        #pragma unroll
        for (int g = 0; g < 4; ++g) pr[m][g] = 0.f;

    #pragma unroll
    for (int n4 = 0; n4 < 4; ++n4) {
        int n = wv * 64 + n4 * 16 + l15;
        float b1v = b1[n];
        float w2v = W2[n];
        #pragma unroll
        for (int m = 0; m < 4; ++m)
            #pragma unroll
            for (int g = 0; g < 4; ++g) {
                float h = acc[m][n4][g] + b1v;
                h = h > 0.f ? h : 0.f;
                pr[m][g] += h * w2v;
            }
    }

    // reduce over the 16 cols held across l15 lanes
    #pragma unroll
    for (int msk = 8; msk >= 1; msk >>= 1) {
        #pragma unroll
        for (int m = 0; m < 4; ++m)
            #pragma unroll
            for (int g = 0; g < 4; ++g)
                pr[m][g] += __shfl_xor(pr[m][g], msk, 64);
    }

    if (l15 == 0) {
        #pragma unroll
        for (int m = 0; m < 4; ++m)
            #pragma unroll
            for (int g = 0; g < 4; ++g)
                partial[wv * 64 + m * 16 + lg * 4 + g] = pr[m][g];
    }
    __syncthreads();

    // final cross-wave sum + sigmoid
    if (t < 64) {
        float s = partial[t] + partial[64 + t] + partial[128 + t] + partial[192 + t] + b2[0];
        out[e0 + t] = 1.0f / (1.0f + __expf(-s));
    }
}

extern "C" void kernel_launch(void* const* d_in, const int* in_sizes, int n_in,
                              void* d_out, int out_size, void* d_ws, size_t ws_size,
                              hipStream_t stream) {
    const float* emd  = (const float*)d_in[0];
    const int*   eidx = (const int*)d_in[1];
    const float* W1   = (const float*)d_in[2];
    const float* b1   = (const float*)d_in[3];
    const float* W2   = (const float*)d_in[4];
    const float* b2   = (const float*)d_in[5];
    float* out = (float*)d_out;
    unsigned short* w1f = (unsigned short*)d_ws;   // 256*256 bf16 = 128KB, fragment-ordered

    prep_w1f<<<256, 256, 0, stream>>>(W1, w1f);

    const int nblocks = N_EDGES_C / 64;            // 9375, exact
    const size_t lds_bytes = 64 * 512 + 4 * 64 * sizeof(float);  // 33792
    edge_mlp<<<nblocks, 256, lds_bytes, stream>>>(emd, eidx, w1f, b1, W2, b2, out);
}